// Round 1
// baseline (465.264 us; speedup 1.0000x reference)
//
#include <hip/hip_runtime.h>
#include <stdint.h>

#define NTOK 256
#define CDIM 64

typedef __attribute__((ext_vector_type(8))) short bf16x8;
typedef __attribute__((ext_vector_type(4))) short bf16x4;
typedef __attribute__((ext_vector_type(4))) float f32x4;

// ---- LDS layout (bytes) ----
// XL/XR: x (bf16, swizzled) -> later overwritten by v_l^T / v_r^T ([64][256] bf16)
// QL/QR: q (bf16, swizzled)
// SW:    2 x [64][64] bf16 transposed weights (W'q then Wv)   [dead after phase 3]
// SP:    per-wave private P chunks (16 rows x 80B)            [lives in SW region, used phase 4+]
#define XL_O 0
#define XR_O 32768
#define QL_O 65536
#define QR_O 98304
#define SW_O 131072
#define SP_O 131072
#define SMEAN_O 147456
#define SRSTD_O 149504
#define SCS_O   151552
#define SQB_O   152064
#define LDS_SIZE 152576

#define MFMA16(a,b,c) __builtin_amdgcn_mfma_f32_16x16x32_bf16((a),(b),(c),0,0,0)

__device__ __forceinline__ short f2bf(float f) {
  union { float f; unsigned u; } v; v.f = f;
  unsigned r = v.u + 0x7fffu + ((v.u >> 16) & 1u);
  return (short)(r >> 16);
}
// 128B-row buffers (x, q, Wt): byte ^= (row&7)<<4 breaks the 32-way column conflict (G4)
__device__ __forceinline__ int swzA(int row, int kb) { return (row << 7) + (kb ^ ((row & 7) << 4)); }
// 512B-row buffers (v^T)
__device__ __forceinline__ int swzV(int row, int kb) { return (row << 9) + (kb ^ ((row & 7) << 4)); }

__global__ __launch_bounds__(512, 2) void scam_kernel(
    const float* __restrict__ xl, const float* __restrict__ xr,
    const float* __restrict__ lsl, const float* __restrict__ lbl,
    const float* __restrict__ lsr, const float* __restrict__ lbr,
    const float* __restrict__ Wql, const float* __restrict__ bql,
    const float* __restrict__ Wqr, const float* __restrict__ bqr,
    const float* __restrict__ Wvl, const float* __restrict__ bvl,
    const float* __restrict__ Wvr, const float* __restrict__ bvr,
    const float* __restrict__ beta, const float* __restrict__ gamma,
    float* __restrict__ outp)
{
  extern __shared__ char sm[];
  const int tid  = threadIdx.x;
  const int lane = tid & 63;
  const int wid  = tid >> 6;
  const int l15  = lane & 15;
  const int l4   = lane >> 4;
  const size_t xbase = (size_t)blockIdx.x * (NTOK * CDIM);

  f32x4 zz = {0.f, 0.f, 0.f, 0.f};

  // ===== Phase 1: stage x (fp32 global -> bf16 LDS, swizzled) + LN stats =====
  #pragma unroll
  for (int side = 0; side < 2; ++side) {
    const float* xp = (side ? xr : xl) + xbase;
    const int XB = side ? XR_O : XL_O;
    #pragma unroll
    for (int rr = 0; rr < 8; ++rr) {
      const int row = rr * 32 + (tid >> 4);
      const int c0  = (tid & 15) << 2;
      const f32x4 v = *(const f32x4*)(xp + row * 64 + c0);
      float s1 = v.x + v.y + v.z + v.w;
      float s2 = v.x * v.x + v.y * v.y + v.z * v.z + v.w * v.w;
      #pragma unroll
      for (int m = 1; m < 16; m <<= 1) { s1 += __shfl_xor(s1, m, 64); s2 += __shfl_xor(s2, m, 64); }
      const float mean = s1 * 0.015625f;
      const float rstd = rsqrtf(s2 * 0.015625f - mean * mean + 1e-6f);
      if ((tid & 15) == 0) {
        ((float*)(sm + SMEAN_O))[side * 256 + row] = mean;
        ((float*)(sm + SRSTD_O))[side * 256 + row] = rstd;
      }
      bf16x4 h;
      h[0] = f2bf(v.x); h[1] = f2bf(v.y); h[2] = f2bf(v.z); h[3] = f2bf(v.w);
      *(bf16x4*)(sm + XB + swzA(row, c0 * 2)) = h;
    }
  }

  // ===== Phase 0b: stage (s .* Wq)^T as bf16 (B-operand wants contiguous k=c) =====
  {
    const int side = tid >> 8;
    const float* Wq = side ? Wqr : Wql;
    const float* sv = side ? lsr : lsl;
    const int c  = (tid >> 2) & 63;
    const int j0 = (tid & 3) << 4;
    const float sc = sv[c];
    const float* src = Wq + c * 64 + j0;
    #pragma unroll
    for (int i = 0; i < 16; ++i)
      *(short*)(sm + SW_O + side * 8192 + swzA(j0 + i, c * 2)) = f2bf(sc * src[i]);
  }
  // ===== Phase 0c: colsum(s.*Wq) and fused bias (lnbias@Wq + bq) =====
  if (tid < 128) {
    const int side = tid >> 6;
    const int j = tid & 63;
    const float* Wq = side ? Wqr : Wql;
    const float* sv = side ? lsr : lsl;
    const float* bv = side ? lbr : lbl;
    const float* bq = side ? bqr : bql;
    float cs = 0.f, qb = 0.f;
    #pragma unroll 8
    for (int c = 0; c < 64; ++c) { const float w = Wq[c * 64 + j]; cs += sv[c] * w; qb += bv[c] * w; }
    ((float*)(sm + SCS_O))[side * 64 + j] = cs;
    ((float*)(sm + SQB_O))[side * 64 + j] = qb + bq[j];
  }
  __syncthreads();

  // ===== Phase 2: q GEMM  q = rstd*(x@W' - mean*colsum) + qb  -> sQ (bf16) =====
  {
    const int side = wid >> 2;
    const int R0 = (wid & 3) * 64;
    const int XB = side ? XR_O : XL_O;
    const int QB = side ? QR_O : QL_O;
    const int WB = SW_O + side * 8192;
    bf16x8 a[4][2];
    #pragma unroll
    for (int rt = 0; rt < 4; ++rt)
      #pragma unroll
      for (int k = 0; k < 2; ++k)
        a[rt][k] = *(bf16x8*)(sm + XB + swzA(R0 + rt * 16 + l15, k * 64 + l4 * 16));
    f32x4 acc[4][4];
    #pragma unroll
    for (int rt = 0; rt < 4; ++rt)
      #pragma unroll
      for (int ct = 0; ct < 4; ++ct) acc[rt][ct] = zz;
    #pragma unroll
    for (int ct = 0; ct < 4; ++ct) {
      const bf16x8 b0 = *(bf16x8*)(sm + WB + swzA(ct * 16 + l15, l4 * 16));
      const bf16x8 b1 = *(bf16x8*)(sm + WB + swzA(ct * 16 + l15, 64 + l4 * 16));
      #pragma unroll
      for (int rt = 0; rt < 4; ++rt) {
        acc[rt][ct] = MFMA16(a[rt][0], b0, acc[rt][ct]);
        acc[rt][ct] = MFMA16(a[rt][1], b1, acc[rt][ct]);
      }
    }
    const float* smean = (const float*)(sm + SMEAN_O) + side * 256;
    const float* srstd = (const float*)(sm + SRSTD_O) + side * 256;
    const float* scs   = (const float*)(sm + SCS_O) + side * 64;
    const float* sqb   = (const float*)(sm + SQB_O) + side * 64;
    float csv[4], qbv[4];
    #pragma unroll
    for (int ct = 0; ct < 4; ++ct) { csv[ct] = scs[ct * 16 + l15]; qbv[ct] = sqb[ct * 16 + l15]; }
    #pragma unroll
    for (int rt = 0; rt < 4; ++rt)
      #pragma unroll
      for (int r = 0; r < 4; ++r) {
        const int row = R0 + rt * 16 + l4 * 4 + r;
        const float m = smean[row], rs = srstd[row];
        #pragma unroll
        for (int ct = 0; ct < 4; ++ct) {
          const float q = rs * (acc[rt][ct][r] - m * csv[ct]) + qbv[ct];
          *(short*)(sm + QB + swzA(row, (ct * 16 + l15) * 2)) = f2bf(q);
        }
      }
  }
  __syncthreads();

  // ===== Phase 3a: stage Wv^T bf16 (overwrites W'q) =====
  {
    const int side = tid >> 8;
    const float* Wv = side ? Wvr : Wvl;
    const int c  = (tid >> 2) & 63;
    const int j0 = (tid & 3) << 4;
    const float* src = Wv + c * 64 + j0;
    #pragma unroll
    for (int i = 0; i < 16; ++i)
      *(short*)(sm + SW_O + side * 8192 + swzA(j0 + i, c * 2)) = f2bf(src[i]);
  }
  __syncthreads();

  // ===== Phase 3b: v GEMM; write v^T bf16 over the x buffers =====
  {
    const int side = wid >> 2;
    const int R0 = (wid & 3) * 64;
    const int XB = side ? XR_O : XL_O;
    const int WB = SW_O + side * 8192;
    const float* bvp = side ? bvr : bvl;
    bf16x8 a[4][2];
    #pragma unroll
    for (int rt = 0; rt < 4; ++rt)
      #pragma unroll
      for (int k = 0; k < 2; ++k)
        a[rt][k] = *(bf16x8*)(sm + XB + swzA(R0 + rt * 16 + l15, k * 64 + l4 * 16));
    f32x4 acc[4][4];
    #pragma unroll
    for (int rt = 0; rt < 4; ++rt)
      #pragma unroll
      for (int ct = 0; ct < 4; ++ct) acc[rt][ct] = zz;
    #pragma unroll
    for (int ct = 0; ct < 4; ++ct) {
      const bf16x8 b0 = *(bf16x8*)(sm + WB + swzA(ct * 16 + l15, l4 * 16));
      const bf16x8 b1 = *(bf16x8*)(sm + WB + swzA(ct * 16 + l15, 64 + l4 * 16));
      #pragma unroll
      for (int rt = 0; rt < 4; ++rt) {
        acc[rt][ct] = MFMA16(a[rt][0], b0, acc[rt][ct]);
        acc[rt][ct] = MFMA16(a[rt][1], b1, acc[rt][ct]);
      }
    }
    float bvv[4];
    #pragma unroll
    for (int ct = 0; ct < 4; ++ct) bvv[ct] = bvp[ct * 16 + l15];
    __syncthreads();   // all x reads done before v^T overwrite
    #pragma unroll
    for (int rt = 0; rt < 4; ++rt) {
      const int t0 = R0 + rt * 16 + l4 * 4;
      #pragma unroll
      for (int ct = 0; ct < 4; ++ct) {
        const int j = ct * 16 + l15;
        bf16x4 h;
        h[0] = f2bf(acc[rt][ct][0] + bvv[ct]);
        h[1] = f2bf(acc[rt][ct][1] + bvv[ct]);
        h[2] = f2bf(acc[rt][ct][2] + bvv[ct]);
        h[3] = f2bf(acc[rt][ct][3] + bvv[ct]);
        *(bf16x4*)(sm + XB + swzV(j, t0 * 2)) = h;
      }
    }
  }
  __syncthreads();

  // ===== Phase 4/5: two flash passes. p=0: attn=ql@qr^T row-softmax @v_r -> out_l
  //                                    p=1: attn^T=qr@ql^T row-softmax @v_l -> out_r
  const float kf = 0.18033688011112042f;   // 0.125 * log2(e)
  #pragma unroll 1
  for (int p = 0; p < 2; ++p) {
    const int QA  = p ? QR_O : QL_O;
    const int QBm = p ? QL_O : QR_O;
    const int VB  = p ? XL_O : XR_O;   // v_l^T lives in XL, v_r^T in XR
    const float* resid = (p ? xr : xl) + xbase;
    const float* gv = p ? gamma : beta;
    float* o = outp + (size_t)p * (4ULL * 256 * 256 * 64) + xbase;
    #pragma unroll 1
    for (int half = 0; half < 2; ++half) {
      const int W0 = wid * 32 + half * 16;   // 16 attn rows per half
      const bf16x8 a0 = *(bf16x8*)(sm + QA + swzA(W0 + l15, l4 * 16));
      const bf16x8 a1 = *(bf16x8*)(sm + QA + swzA(W0 + l15, 64 + l4 * 16));
      f32x4 pacc[16];
      #pragma unroll
      for (int ct = 0; ct < 16; ++ct) pacc[ct] = zz;
      #pragma unroll
      for (int ct = 0; ct < 16; ++ct) {
        const bf16x8 b0 = *(bf16x8*)(sm + QBm + swzA(ct * 16 + l15, l4 * 16));
        const bf16x8 b1 = *(bf16x8*)(sm + QBm + swzA(ct * 16 + l15, 64 + l4 * 16));
        pacc[ct] = MFMA16(a0, b0, pacc[ct]);
        pacc[ct] = MFMA16(a1, b1, pacc[ct]);
      }
      // row softmax (rows are wave-local): max, exp2, sum; keep 1/sum
      float rsv[4];
      #pragma unroll
      for (int r = 0; r < 4; ++r) {
        float mx = pacc[0][r];
        #pragma unroll
        for (int ct = 1; ct < 16; ++ct) mx = fmaxf(mx, pacc[ct][r]);
        #pragma unroll
        for (int m = 1; m < 16; m <<= 1) mx = fmaxf(mx, __shfl_xor(mx, m, 64));
        float sum = 0.f;
        #pragma unroll
        for (int ct = 0; ct < 16; ++ct) {
          const float e = exp2f((pacc[ct][r] - mx) * kf);
          pacc[ct][r] = e;
          sum += e;
        }
        #pragma unroll
        for (int m = 1; m < 16; m <<= 1) sum += __shfl_xor(sum, m, 64);
        rsv[r] = 1.f / sum;
      }
      // PV: stream P through a private LDS chunk (acc layout -> A-frag layout)
      f32x4 facc[4];
      #pragma unroll
      for (int cv = 0; cv < 4; ++cv) facc[cv] = zz;
      const int SPw = SP_O + wid * 1280;   // 16 rows x 80B, pad stride => ~conflict-free
      #pragma unroll 1
      for (int ch = 0; ch < 8; ++ch) {
        #pragma unroll
        for (int t2 = 0; t2 < 2; ++t2) {
          const int ct = ch * 2 + t2;
          #pragma unroll
          for (int r = 0; r < 4; ++r)
            *(short*)(sm + SPw + (l4 * 4 + r) * 80 + (t2 * 16 + l15) * 2) = f2bf(pacc[ct][r]);
        }
        asm volatile("s_waitcnt lgkmcnt(0)" ::: "memory");
        const bf16x8 pa = *(bf16x8*)(sm + SPw + l15 * 80 + l4 * 16);
        #pragma unroll
        for (int cv = 0; cv < 4; ++cv) {
          const bf16x8 b = *(bf16x8*)(sm + VB + swzV(cv * 16 + l15, ch * 64 + l4 * 16));
          facc[cv] = MFMA16(pa, b, facc[cv]);
        }
      }
      // epilogue: out = x + gv * facc / rowsum
      #pragma unroll
      for (int r = 0; r < 4; ++r) {
        const int row = W0 + l4 * 4 + r;
        const float rs = rsv[r];
        #pragma unroll
        for (int cv = 0; cv < 4; ++cv) {
          const int j = cv * 16 + l15;
          o[row * 64 + j] = resid[row * 64 + j] + gv[j] * facc[cv][r] * rs;
        }
      }
    }
  }
}

extern "C" void kernel_launch(void* const* d_in, const int* in_sizes, int n_in,
                              void* d_out, int out_size, void* d_ws, size_t ws_size,
                              hipStream_t stream) {
  hipFuncSetAttribute(reinterpret_cast<const void*>(scam_kernel),
                      hipFuncAttributeMaxDynamicSharedMemorySize, LDS_SIZE);
  scam_kernel<<<dim3(1024), dim3(512), LDS_SIZE, stream>>>(
      (const float*)d_in[0],  (const float*)d_in[1],
      (const float*)d_in[2],  (const float*)d_in[3],
      (const float*)d_in[4],  (const float*)d_in[5],
      (const float*)d_in[6],  (const float*)d_in[7],
      (const float*)d_in[8],  (const float*)d_in[9],
      (const float*)d_in[10], (const float*)d_in[11],
      (const float*)d_in[12], (const float*)d_in[13],
      (const float*)d_in[14], (const float*)d_in[15],
      (float*)d_out);
}